// Round 1
// baseline (3335.242 us; speedup 1.0000x reference)
//
#include <hip/hip_runtime.h>

#define BATCH 16
#define CH 64
#define NPTS 65536
#define RX 32
#define RY 32
#define RZ 32
#define RVOX (RX * RY * RZ)  // 32768

// ---------------- K1: per-batch coordinate mean (double accumulation) ----------------
__global__ void mean_kernel(const float* __restrict__ coords, double* __restrict__ meanAcc) {
    const int b = blockIdx.y;
    const int tid = threadIdx.x;
    const float* cb = coords + (size_t)b * 3 * NPTS;
    double sx = 0.0, sy = 0.0, sz = 0.0;
    for (int n = blockIdx.x * blockDim.x + tid; n < NPTS; n += gridDim.x * blockDim.x) {
        sx += (double)cb[n];
        sy += (double)cb[NPTS + n];
        sz += (double)cb[2 * NPTS + n];
    }
    for (int off = 32; off > 0; off >>= 1) {
        sx += __shfl_down(sx, off);
        sy += __shfl_down(sy, off);
        sz += __shfl_down(sz, off);
    }
    __shared__ double red[3][4];
    const int wave = tid >> 6, lane = tid & 63;
    if (lane == 0) { red[0][wave] = sx; red[1][wave] = sy; red[2][wave] = sz; }
    __syncthreads();
    if (tid == 0) {
        double tx = 0, ty = 0, tz = 0;
        const int nw = blockDim.x >> 6;
        for (int w = 0; w < nw; ++w) { tx += red[0][w]; ty += red[1][w]; tz += red[2][w]; }
        atomicAdd(&meanAcc[b * 3 + 0], tx);
        atomicAdd(&meanAcc[b * 3 + 1], ty);
        atomicAdd(&meanAcc[b * 3 + 2], tz);
    }
}

// ---------------- K2: per-batch max of squared norm ----------------
__global__ void maxnorm_kernel(const float* __restrict__ coords,
                               const double* __restrict__ meanAcc,
                               int* __restrict__ maxAcc) {
    const int b = blockIdx.y;
    const int tid = threadIdx.x;
    const float* cb = coords + (size_t)b * 3 * NPTS;
    const float mx = (float)(meanAcc[b * 3 + 0] * (1.0 / NPTS));
    const float my = (float)(meanAcc[b * 3 + 1] * (1.0 / NPTS));
    const float mz = (float)(meanAcc[b * 3 + 2] * (1.0 / NPTS));
    float m = 0.0f;
    for (int n = blockIdx.x * blockDim.x + tid; n < NPTS; n += gridDim.x * blockDim.x) {
        const float dx = cb[n] - mx;
        const float dy = cb[NPTS + n] - my;
        const float dz = cb[2 * NPTS + n] - mz;
        const float n2 = dx * dx + dy * dy + dz * dz;
        m = fmaxf(m, n2);
    }
    for (int off = 32; off > 0; off >>= 1) m = fmaxf(m, __shfl_down(m, off));
    __shared__ float redm[4];
    const int wave = tid >> 6, lane = tid & 63;
    if (lane == 0) redm[wave] = m;
    __syncthreads();
    if (tid == 0) {
        float t = redm[0];
        const int nw = blockDim.x >> 6;
        for (int w = 1; w < nw; ++w) t = fmaxf(t, redm[w]);
        atomicMax(&maxAcc[b], __float_as_int(t));  // norm2 >= 0 -> int-bit compare valid
    }
}

// ---------------- K3: per-point normalize + voxel index + counts ----------------
__global__ void point_kernel(const float* __restrict__ coords,
                             const double* __restrict__ meanAcc,
                             const int* __restrict__ maxAcc,
                             float* __restrict__ normc,
                             int* __restrict__ idxArr,
                             float* __restrict__ counts) {
    const int t = blockIdx.x * blockDim.x + threadIdx.x;  // [0, BATCH*NPTS)
    const int b = t >> 16;
    const int n = t & (NPTS - 1);
    const float denom = 2.0f * sqrtf(__int_as_float(maxAcc[b]));
    int vi[3];
#pragma unroll
    for (int d = 0; d < 3; ++d) {
        const float m = (float)(meanAcc[b * 3 + d] * (1.0 / NPTS));
        const float v = coords[((size_t)b * 3 + d) * NPTS + n];
        float s = ((v - m) / denom + 0.5f) * 32.0f;
        s = fminf(fmaxf(s, 0.0f), 31.0f);
        normc[((size_t)b * 3 + d) * NPTS + n] = s;
        vi[d] = (int)rintf(s);  // half-to-even, matches jnp.round
    }
    const int idx = vi[0] * (RY * RZ) + vi[1] * RZ + vi[2];
    idxArr[t] = idx;
    atomicAdd(&counts[b * RVOX + idx], 1.0f);
}

// ---------------- K4: scatter-add features into the voxel grid ----------------
__global__ void scatter_kernel(const float* __restrict__ features,
                               const int* __restrict__ idxArr,
                               float* __restrict__ out) {
    const size_t t = (size_t)blockIdx.x * blockDim.x + threadIdx.x;  // over B*C*N/4
    const size_t base = t * 4;
    const int n = (int)(base & (NPTS - 1));
    const int bc = (int)(base >> 16);  // b*CH + c
    const int b = bc >> 6;
    const float4 f = ((const float4*)features)[t];
    const int4 id4 = *(const int4*)(idxArr + (size_t)b * NPTS + n);
    float* o = out + (size_t)bc * RVOX;
    atomicAdd(o + id4.x, f.x);
    atomicAdd(o + id4.y, f.y);
    atomicAdd(o + id4.z, f.z);
    atomicAdd(o + id4.w, f.w);
}

// ---------------- K5: divide by counts, in place ----------------
__global__ void finalize_kernel(float* __restrict__ out, const float* __restrict__ counts) {
    const size_t t = (size_t)blockIdx.x * blockDim.x + threadIdx.x;  // over B*C*R/4
    const size_t base = t * 4;
    const int r = (int)(base & (RVOX - 1));
    const int bc = (int)(base >> 15);
    const int b = bc >> 6;
    float4 v = ((float4*)out)[t];
    const float4 c4 = *(const float4*)(counts + (size_t)b * RVOX + r);
    v.x /= fmaxf(c4.x, 1.0f);
    v.y /= fmaxf(c4.y, 1.0f);
    v.z /= fmaxf(c4.z, 1.0f);
    v.w /= fmaxf(c4.w, 1.0f);
    ((float4*)out)[t] = v;
}

extern "C" void kernel_launch(void* const* d_in, const int* in_sizes, int n_in,
                              void* d_out, int out_size, void* d_ws, size_t ws_size,
                              hipStream_t stream) {
    const float* features = (const float*)d_in[0];  // [16, 64, 65536]
    const float* coords = (const float*)d_in[1];    // [16, 3, 65536]
    float* out = (float*)d_out;                              // [16,64,32,32,32]
    float* normc = out + (size_t)BATCH * CH * RVOX;          // [16,3,65536]

    // ws layout: [0,384) double meanAcc[16*3]; [384,448) int maxAcc[16];
    //            [512, 512+2MiB) float counts[16*32768]; then int idx[16*65536]
    char* ws = (char*)d_ws;
    double* meanAcc = (double*)ws;
    int* maxAcc = (int*)(ws + 384);
    float* counts = (float*)(ws + 512);
    int* idxArr = (int*)(ws + 512 + (size_t)BATCH * RVOX * 4);

    hipMemsetAsync(out, 0, (size_t)BATCH * CH * RVOX * sizeof(float), stream);
    hipMemsetAsync(ws, 0, 512 + (size_t)BATCH * RVOX * 4, stream);

    dim3 gred(32, BATCH);
    mean_kernel<<<gred, 256, 0, stream>>>(coords, meanAcc);
    maxnorm_kernel<<<gred, 256, 0, stream>>>(coords, meanAcc, maxAcc);

    point_kernel<<<(BATCH * NPTS) / 256, 256, 0, stream>>>(coords, meanAcc, maxAcc,
                                                           normc, idxArr, counts);

    scatter_kernel<<<((size_t)BATCH * CH * NPTS / 4) / 256, 256, 0, stream>>>(features, idxArr, out);

    finalize_kernel<<<((size_t)BATCH * CH * RVOX / 4) / 256, 256, 0, stream>>>(out, counts);
}

// Round 2
// 736.090 us; speedup vs baseline: 4.5310x; 4.5310x over previous
//
#include <hip/hip_runtime.h>

#define BATCH 16
#define CH 64
#define NPTS 65536
#define RX 32
#define RY 32
#define RZ 32
#define RVOX (RX * RY * RZ)   // 32768
#define HALFVOX (RVOX / 2)    // 16384 floats = 64 KB in LDS

// ---------------- K1: per-batch coordinate mean (double accumulation) ----------------
__global__ void mean_kernel(const float* __restrict__ coords, double* __restrict__ meanAcc) {
    const int b = blockIdx.y;
    const int tid = threadIdx.x;
    const float* cb = coords + (size_t)b * 3 * NPTS;
    double sx = 0.0, sy = 0.0, sz = 0.0;
    for (int n = blockIdx.x * blockDim.x + tid; n < NPTS; n += gridDim.x * blockDim.x) {
        sx += (double)cb[n];
        sy += (double)cb[NPTS + n];
        sz += (double)cb[2 * NPTS + n];
    }
    for (int off = 32; off > 0; off >>= 1) {
        sx += __shfl_down(sx, off);
        sy += __shfl_down(sy, off);
        sz += __shfl_down(sz, off);
    }
    __shared__ double red[3][4];
    const int wave = tid >> 6, lane = tid & 63;
    if (lane == 0) { red[0][wave] = sx; red[1][wave] = sy; red[2][wave] = sz; }
    __syncthreads();
    if (tid == 0) {
        double tx = 0, ty = 0, tz = 0;
        const int nw = blockDim.x >> 6;
        for (int w = 0; w < nw; ++w) { tx += red[0][w]; ty += red[1][w]; tz += red[2][w]; }
        atomicAdd(&meanAcc[b * 3 + 0], tx);
        atomicAdd(&meanAcc[b * 3 + 1], ty);
        atomicAdd(&meanAcc[b * 3 + 2], tz);
    }
}

// ---------------- K2: per-batch max of squared norm ----------------
__global__ void maxnorm_kernel(const float* __restrict__ coords,
                               const double* __restrict__ meanAcc,
                               int* __restrict__ maxAcc) {
    const int b = blockIdx.y;
    const int tid = threadIdx.x;
    const float* cb = coords + (size_t)b * 3 * NPTS;
    const float mx = (float)(meanAcc[b * 3 + 0] * (1.0 / NPTS));
    const float my = (float)(meanAcc[b * 3 + 1] * (1.0 / NPTS));
    const float mz = (float)(meanAcc[b * 3 + 2] * (1.0 / NPTS));
    float m = 0.0f;
    for (int n = blockIdx.x * blockDim.x + tid; n < NPTS; n += gridDim.x * blockDim.x) {
        const float dx = cb[n] - mx;
        const float dy = cb[NPTS + n] - my;
        const float dz = cb[2 * NPTS + n] - mz;
        const float n2 = dx * dx + dy * dy + dz * dz;
        m = fmaxf(m, n2);
    }
    for (int off = 32; off > 0; off >>= 1) m = fmaxf(m, __shfl_down(m, off));
    __shared__ float redm[4];
    const int wave = tid >> 6, lane = tid & 63;
    if (lane == 0) redm[wave] = m;
    __syncthreads();
    if (tid == 0) {
        float t = redm[0];
        const int nw = blockDim.x >> 6;
        for (int w = 1; w < nw; ++w) t = fmaxf(t, redm[w]);
        atomicMax(&maxAcc[b], __float_as_int(t));  // norm2 >= 0 -> int-bit compare valid
    }
}

// ---------------- K3: per-point normalize + voxel index (u16) + counts ----------------
__global__ void point_kernel(const float* __restrict__ coords,
                             const double* __restrict__ meanAcc,
                             const int* __restrict__ maxAcc,
                             float* __restrict__ normc,
                             unsigned short* __restrict__ idx16,
                             float* __restrict__ counts) {
    const int t = blockIdx.x * blockDim.x + threadIdx.x;  // [0, BATCH*NPTS)
    const int b = t >> 16;
    const int n = t & (NPTS - 1);
    const float denom = 2.0f * sqrtf(__int_as_float(maxAcc[b]));
    int vi[3];
#pragma unroll
    for (int d = 0; d < 3; ++d) {
        const float m = (float)(meanAcc[b * 3 + d] * (1.0 / NPTS));
        const float v = coords[((size_t)b * 3 + d) * NPTS + n];
        float s = ((v - m) / denom + 0.5f) * 32.0f;
        s = fminf(fmaxf(s, 0.0f), 31.0f);
        normc[((size_t)b * 3 + d) * NPTS + n] = s;
        vi[d] = (int)rintf(s);  // half-to-even, matches jnp.round
    }
    const int idx = vi[0] * (RY * RZ) + vi[1] * RZ + vi[2];  // < 32768, fits u16
    idx16[t] = (unsigned short)idx;
    atomicAdd(&counts[b * RVOX + idx], 1.0f);
}

// ---------------- K4: per-(b,c) LDS-privatized accumulation, 2 half-grid passes ----------
// grid = (CH, BATCH), block = 1024. 64 KB static LDS -> 2 blocks/CU, 32 waves/CU.
__global__ __launch_bounds__(1024) void accum_kernel(const float* __restrict__ features,
                                                     const unsigned short* __restrict__ idx16,
                                                     const float* __restrict__ counts,
                                                     float* __restrict__ out) {
    __shared__ float g[HALFVOX];  // 64 KB
    const int c = blockIdx.x;
    const int b = blockIdx.y;
    const int tid = threadIdx.x;
    const float* fs = features + ((size_t)(b * CH + c)) * NPTS;
    const unsigned short* is = idx16 + (size_t)b * NPTS;
    const float* cb = counts + (size_t)b * RVOX;
    float* ob = out + ((size_t)(b * CH + c)) * RVOX;

#pragma unroll
    for (int half = 0; half < 2; ++half) {
        // zero the half-grid
        for (int i = tid; i < HALFVOX; i += 1024) g[i] = 0.0f;
        __syncthreads();
        // stream points coalesced; accumulate the ones in this x-half
        const unsigned short want = (unsigned short)half;
        for (int i = tid; i < NPTS / 4; i += 1024) {
            const float4 fv = ((const float4*)fs)[i];
            const ushort4 iv = ((const ushort4*)is)[i];
            if ((iv.x >> 14) == want) atomicAdd(&g[iv.x & (HALFVOX - 1)], fv.x);
            if ((iv.y >> 14) == want) atomicAdd(&g[iv.y & (HALFVOX - 1)], fv.y);
            if ((iv.z >> 14) == want) atomicAdd(&g[iv.z & (HALFVOX - 1)], fv.z);
            if ((iv.w >> 14) == want) atomicAdd(&g[iv.w & (HALFVOX - 1)], fv.w);
        }
        __syncthreads();
        // write out this half, fused divide-by-count
        const float* ch = cb + half * HALFVOX;
        float* oh = ob + half * HALFVOX;
        for (int i = tid; i < HALFVOX / 4; i += 1024) {
            const float4 c4 = ((const float4*)ch)[i];
            float4 v = ((const float4*)g)[i];
            v.x /= fmaxf(c4.x, 1.0f);
            v.y /= fmaxf(c4.y, 1.0f);
            v.z /= fmaxf(c4.z, 1.0f);
            v.w /= fmaxf(c4.w, 1.0f);
            ((float4*)oh)[i] = v;
        }
        __syncthreads();  // protect g before next-half re-zero
    }
}

extern "C" void kernel_launch(void* const* d_in, const int* in_sizes, int n_in,
                              void* d_out, int out_size, void* d_ws, size_t ws_size,
                              hipStream_t stream) {
    const float* features = (const float*)d_in[0];  // [16, 64, 65536]
    const float* coords = (const float*)d_in[1];    // [16, 3, 65536]
    float* out = (float*)d_out;                              // [16,64,32,32,32]
    float* normc = out + (size_t)BATCH * CH * RVOX;          // [16,3,65536]

    // ws layout: [0,384) double meanAcc[16*3]; [384,448) int maxAcc[16];
    //            [512, 512+2MiB) float counts[16*32768];
    //            then ushort idx16[16*65536] (2 MiB)
    char* ws = (char*)d_ws;
    double* meanAcc = (double*)ws;
    int* maxAcc = (int*)(ws + 384);
    float* counts = (float*)(ws + 512);
    unsigned short* idx16 = (unsigned short*)(ws + 512 + (size_t)BATCH * RVOX * 4);

    hipMemsetAsync(ws, 0, 512 + (size_t)BATCH * RVOX * 4, stream);

    dim3 gred(32, BATCH);
    mean_kernel<<<gred, 256, 0, stream>>>(coords, meanAcc);
    maxnorm_kernel<<<gred, 256, 0, stream>>>(coords, meanAcc, maxAcc);

    point_kernel<<<(BATCH * NPTS) / 256, 256, 0, stream>>>(coords, meanAcc, maxAcc,
                                                           normc, idx16, counts);

    accum_kernel<<<dim3(CH, BATCH), 1024, 0, stream>>>(features, idx16, counts, out);
}

// Round 3
// 729.308 us; speedup vs baseline: 4.5732x; 1.0093x over previous
//
#include <hip/hip_runtime.h>

#define BATCH 16
#define CH 64
#define NPTS 65536
#define RX 32
#define RY 32
#define RZ 32
#define RVOX (RX * RY * RZ)   // 32768
#define HALFVOX (RVOX / 2)    // 16384 floats = 64 KB in LDS
#define NQ (NPTS / 4)         // 16384 float4 quads per (b, plane)

// ---------------- K1: per-batch coordinate mean (double accumulation) ----------------
// grid (64, BATCH) x 256: one float4 per thread per component.
__global__ void mean_kernel(const float* __restrict__ coords, double* __restrict__ meanAcc) {
    const int b = blockIdx.y;
    const int t = blockIdx.x * blockDim.x + threadIdx.x;  // [0, NQ)
    const float4* cb = (const float4*)(coords + (size_t)b * 3 * NPTS);
    double s[3];
#pragma unroll
    for (int d = 0; d < 3; ++d) {
        const float4 v = cb[d * NQ + t];
        s[d] = ((double)v.x + (double)v.y) + ((double)v.z + (double)v.w);
    }
#pragma unroll
    for (int off = 32; off > 0; off >>= 1) {
        s[0] += __shfl_down(s[0], off);
        s[1] += __shfl_down(s[1], off);
        s[2] += __shfl_down(s[2], off);
    }
    __shared__ double red[3][4];
    const int wave = threadIdx.x >> 6, lane = threadIdx.x & 63;
    if (lane == 0) { red[0][wave] = s[0]; red[1][wave] = s[1]; red[2][wave] = s[2]; }
    __syncthreads();
    if (threadIdx.x == 0) {
        double tx = 0, ty = 0, tz = 0;
        for (int w = 0; w < 4; ++w) { tx += red[0][w]; ty += red[1][w]; tz += red[2][w]; }
        atomicAdd(&meanAcc[b * 3 + 0], tx);
        atomicAdd(&meanAcc[b * 3 + 1], ty);
        atomicAdd(&meanAcc[b * 3 + 2], tz);
    }
}

// ---------------- K2: per-batch max of squared norm ----------------
__global__ void maxnorm_kernel(const float* __restrict__ coords,
                               const double* __restrict__ meanAcc,
                               int* __restrict__ maxAcc) {
    const int b = blockIdx.y;
    const int t = blockIdx.x * blockDim.x + threadIdx.x;  // [0, NQ)
    const float4* cb = (const float4*)(coords + (size_t)b * 3 * NPTS);
    const float mx = (float)(meanAcc[b * 3 + 0] * (1.0 / NPTS));
    const float my = (float)(meanAcc[b * 3 + 1] * (1.0 / NPTS));
    const float mz = (float)(meanAcc[b * 3 + 2] * (1.0 / NPTS));
    const float4 x = cb[0 * NQ + t];
    const float4 y = cb[1 * NQ + t];
    const float4 z = cb[2 * NQ + t];
    float m = 0.0f;
    {
        float dx = x.x - mx, dy = y.x - my, dz = z.x - mz; m = fmaxf(m, dx*dx + dy*dy + dz*dz);
        dx = x.y - mx; dy = y.y - my; dz = z.y - mz;      m = fmaxf(m, dx*dx + dy*dy + dz*dz);
        dx = x.z - mx; dy = y.z - my; dz = z.z - mz;      m = fmaxf(m, dx*dx + dy*dy + dz*dz);
        dx = x.w - mx; dy = y.w - my; dz = z.w - mz;      m = fmaxf(m, dx*dx + dy*dy + dz*dz);
    }
#pragma unroll
    for (int off = 32; off > 0; off >>= 1) m = fmaxf(m, __shfl_down(m, off));
    __shared__ float redm[4];
    const int wave = threadIdx.x >> 6, lane = threadIdx.x & 63;
    if (lane == 0) redm[wave] = m;
    __syncthreads();
    if (threadIdx.x == 0) {
        float tmax = fmaxf(fmaxf(redm[0], redm[1]), fmaxf(redm[2], redm[3]));
        atomicMax(&maxAcc[b], __float_as_int(tmax));  // norm2 >= 0 -> int-bit compare valid
    }
}

// ---------------- K3: per-point normalize + voxel index (u16) + counts ----------------
// one float4 quad (4 points) per thread; t in [0, BATCH*NQ)
__global__ void point_kernel(const float* __restrict__ coords,
                             const double* __restrict__ meanAcc,
                             const int* __restrict__ maxAcc,
                             float* __restrict__ normc,
                             unsigned short* __restrict__ idx16,
                             float* __restrict__ counts) {
    const int t = blockIdx.x * blockDim.x + threadIdx.x;
    const int b = t >> 14;          // NQ = 16384 quads per plane
    const int q = t & (NQ - 1);
    const float denom = 2.0f * sqrtf(__int_as_float(maxAcc[b]));
    const float4* cb = (const float4*)(coords + (size_t)b * 3 * NPTS);
    float4* nb = (float4*)(normc + (size_t)b * 3 * NPTS);
    int vx[3][4];
#pragma unroll
    for (int d = 0; d < 3; ++d) {
        const float m = (float)(meanAcc[b * 3 + d] * (1.0 / NPTS));
        float4 v = cb[d * NQ + q];
        float4 s;
        s.x = fminf(fmaxf(((v.x - m) / denom + 0.5f) * 32.0f, 0.0f), 31.0f);
        s.y = fminf(fmaxf(((v.y - m) / denom + 0.5f) * 32.0f, 0.0f), 31.0f);
        s.z = fminf(fmaxf(((v.z - m) / denom + 0.5f) * 32.0f, 0.0f), 31.0f);
        s.w = fminf(fmaxf(((v.w - m) / denom + 0.5f) * 32.0f, 0.0f), 31.0f);
        nb[d * NQ + q] = s;
        vx[d][0] = (int)rintf(s.x);
        vx[d][1] = (int)rintf(s.y);
        vx[d][2] = (int)rintf(s.z);
        vx[d][3] = (int)rintf(s.w);
    }
    ushort4 o;
    o.x = (unsigned short)(vx[0][0] * (RY * RZ) + vx[1][0] * RZ + vx[2][0]);
    o.y = (unsigned short)(vx[0][1] * (RY * RZ) + vx[1][1] * RZ + vx[2][1]);
    o.z = (unsigned short)(vx[0][2] * (RY * RZ) + vx[1][2] * RZ + vx[2][2]);
    o.w = (unsigned short)(vx[0][3] * (RY * RZ) + vx[1][3] * RZ + vx[2][3]);
    ((ushort4*)(idx16 + (size_t)b * NPTS))[q] = o;
    float* cbp = counts + (size_t)b * RVOX;
    atomicAdd(&cbp[o.x], 1.0f);
    atomicAdd(&cbp[o.y], 1.0f);
    atomicAdd(&cbp[o.z], 1.0f);
    atomicAdd(&cbp[o.w], 1.0f);
}

// ---------------- K4: per-(b,c) LDS-privatized accumulation, 2 half-grid passes ----------
// grid = (CH, BATCH), block = 1024. 64 KB static LDS -> 2 blocks/CU, 32 waves/CU.
// 4x batched loads for memory-level parallelism (8 loads in flight per wave).
__global__ __launch_bounds__(1024) void accum_kernel(const float* __restrict__ features,
                                                     const unsigned short* __restrict__ idx16,
                                                     const float* __restrict__ counts,
                                                     float* __restrict__ out) {
    __shared__ float g[HALFVOX];  // 64 KB
    const int c = blockIdx.x;
    const int b = blockIdx.y;
    const int tid = threadIdx.x;
    const float4* fs = (const float4*)(features + ((size_t)(b * CH + c)) * NPTS);
    const ushort4* is = (const ushort4*)(idx16 + (size_t)b * NPTS);
    const float* cb = counts + (size_t)b * RVOX;
    float* ob = out + ((size_t)(b * CH + c)) * RVOX;

#pragma unroll
    for (int half = 0; half < 2; ++half) {
        for (int i = tid; i < HALFVOX; i += 1024) g[i] = 0.0f;
        __syncthreads();
        const unsigned short want = (unsigned short)half;
        // NQ = 16384 quads, 1024 threads, unroll 4 -> 4 outer iterations
        for (int base = tid; base < NQ; base += 4096) {
            const float4 f0 = fs[base];
            const float4 f1 = fs[base + 1024];
            const float4 f2 = fs[base + 2048];
            const float4 f3 = fs[base + 3072];
            const ushort4 v0 = is[base];
            const ushort4 v1 = is[base + 1024];
            const ushort4 v2 = is[base + 2048];
            const ushort4 v3 = is[base + 3072];
            if ((v0.x >> 14) == want) atomicAdd(&g[v0.x & (HALFVOX - 1)], f0.x);
            if ((v0.y >> 14) == want) atomicAdd(&g[v0.y & (HALFVOX - 1)], f0.y);
            if ((v0.z >> 14) == want) atomicAdd(&g[v0.z & (HALFVOX - 1)], f0.z);
            if ((v0.w >> 14) == want) atomicAdd(&g[v0.w & (HALFVOX - 1)], f0.w);
            if ((v1.x >> 14) == want) atomicAdd(&g[v1.x & (HALFVOX - 1)], f1.x);
            if ((v1.y >> 14) == want) atomicAdd(&g[v1.y & (HALFVOX - 1)], f1.y);
            if ((v1.z >> 14) == want) atomicAdd(&g[v1.z & (HALFVOX - 1)], f1.z);
            if ((v1.w >> 14) == want) atomicAdd(&g[v1.w & (HALFVOX - 1)], f1.w);
            if ((v2.x >> 14) == want) atomicAdd(&g[v2.x & (HALFVOX - 1)], f2.x);
            if ((v2.y >> 14) == want) atomicAdd(&g[v2.y & (HALFVOX - 1)], f2.y);
            if ((v2.z >> 14) == want) atomicAdd(&g[v2.z & (HALFVOX - 1)], f2.z);
            if ((v2.w >> 14) == want) atomicAdd(&g[v2.w & (HALFVOX - 1)], f2.w);
            if ((v3.x >> 14) == want) atomicAdd(&g[v3.x & (HALFVOX - 1)], f3.x);
            if ((v3.y >> 14) == want) atomicAdd(&g[v3.y & (HALFVOX - 1)], f3.y);
            if ((v3.z >> 14) == want) atomicAdd(&g[v3.z & (HALFVOX - 1)], f3.z);
            if ((v3.w >> 14) == want) atomicAdd(&g[v3.w & (HALFVOX - 1)], f3.w);
        }
        __syncthreads();
        // write out this half, fused divide-by-count
        const float* ch = cb + half * HALFVOX;
        float* oh = ob + half * HALFVOX;
        for (int i = tid; i < HALFVOX / 4; i += 1024) {
            const float4 c4 = ((const float4*)ch)[i];
            float4 v = ((const float4*)g)[i];
            v.x /= fmaxf(c4.x, 1.0f);
            v.y /= fmaxf(c4.y, 1.0f);
            v.z /= fmaxf(c4.z, 1.0f);
            v.w /= fmaxf(c4.w, 1.0f);
            ((float4*)oh)[i] = v;
        }
        __syncthreads();  // protect g before next-half re-zero
    }
}

extern "C" void kernel_launch(void* const* d_in, const int* in_sizes, int n_in,
                              void* d_out, int out_size, void* d_ws, size_t ws_size,
                              hipStream_t stream) {
    const float* features = (const float*)d_in[0];  // [16, 64, 65536]
    const float* coords = (const float*)d_in[1];    // [16, 3, 65536]
    float* out = (float*)d_out;                              // [16,64,32,32,32]
    float* normc = out + (size_t)BATCH * CH * RVOX;          // [16,3,65536]

    // ws layout: [0,384) double meanAcc[16*3]; [384,448) int maxAcc[16];
    //            [512, 512+2MiB) float counts[16*32768];
    //            then ushort idx16[16*65536] (2 MiB)
    char* ws = (char*)d_ws;
    double* meanAcc = (double*)ws;
    int* maxAcc = (int*)(ws + 384);
    float* counts = (float*)(ws + 512);
    unsigned short* idx16 = (unsigned short*)(ws + 512 + (size_t)BATCH * RVOX * 4);

    hipMemsetAsync(ws, 0, 512 + (size_t)BATCH * RVOX * 4, stream);

    dim3 gred(NQ / 256, BATCH);  // (64, 16)
    mean_kernel<<<gred, 256, 0, stream>>>(coords, meanAcc);
    maxnorm_kernel<<<gred, 256, 0, stream>>>(coords, meanAcc, maxAcc);

    point_kernel<<<(BATCH * NQ) / 256, 256, 0, stream>>>(coords, meanAcc, maxAcc,
                                                         normc, idx16, counts);

    accum_kernel<<<dim3(CH, BATCH), 1024, 0, stream>>>(features, idx16, counts, out);
}